// Round 3
// baseline (502.589 us; speedup 1.0000x reference)
//
#include <hip/hip_runtime.h>
#include <math.h>

typedef unsigned short ushort_t;
typedef __attribute__((ext_vector_type(8))) short short8;
typedef __attribute__((ext_vector_type(4))) float f32x4;

#define WS_W_USHORTS 173056
#define NTILES 23   // 23 tiles x 16 positions = 368 >= 361

__device__ inline float bf2f(ushort_t h) { return __uint_as_float(((unsigned)h) << 16); }
__device__ inline ushort_t f2bf(float f) {
    unsigned u = __float_as_uint(f);
    return (ushort_t)((u + 0x7FFFu + ((u >> 16) & 1u)) >> 16);
}
// pack two f32 -> (bf16(f0) | bf16(f1)<<16), round-half-away via +0x8000 then v_perm
__device__ inline unsigned pkbf(float f0, float f1) {
    unsigned a = __float_as_uint(f0) + 0x8000u;
    unsigned b = __float_as_uint(f1) + 0x8000u;
    return __builtin_amdgcn_perm(b, a, 0x07060302u);
}
__device__ inline float leaky(float v) { return v >= 0.f ? v : 0.01f * v; }

// ws ushort layout (bf16 MFMA A-fragments, lane-major 16B blocks):
//   L1 @0      : 16 outsub x 16 kstep x 64 lane x 8 = 131072
//   L2 @131072 :  8 outsub x  8 kstep x 64 lane x 8 =  32768
//   L3 @163840 :  4 outsub x  4 kstep x 64 lane x 8 =   8192
//   L4 @172032 :  2 kstep x 64 lane x 8 = 1024 (rows 4..15 zero)
__global__ void pack_weights(const float* __restrict__ w1, const float* __restrict__ w2,
                             const float* __restrict__ w3, const float* __restrict__ w4,
                             ushort_t* __restrict__ ws) {
    int idx = blockIdx.x * 256 + threadIdx.x;
    float val = 0.f;
    if (idx < 131072) {
        int j = idx & 7, u = idx >> 3, lane = u & 63, blk = u >> 6;
        int m = lane & 15, q = lane >> 4;
        int ks = blk & 15, os = blk >> 4;
        val = w1[(os * 16 + m) * 512 + ks * 32 + q * 8 + j];
    } else if (idx < 163840) {
        int l = idx - 131072;
        int j = l & 7, u = l >> 3, lane = u & 63, blk = u >> 6;
        int m = lane & 15, q = lane >> 4;
        int ks = blk & 7, os = blk >> 3;
        val = w2[(os * 16 + m) * 256 + ks * 32 + q * 8 + j];
    } else if (idx < 172032) {
        int l = idx - 163840;
        int j = l & 7, u = l >> 3, lane = u & 63, blk = u >> 6;
        int m = lane & 15, q = lane >> 4;
        int ks = blk & 3, os = blk >> 2;
        val = w3[(os * 16 + m) * 128 + ks * 32 + q * 8 + j];
    } else if (idx < 173056) {
        int l = idx - 172032;
        int j = l & 7, u = l >> 3, lane = u & 63, blk = u >> 6;
        int m = lane & 15, q = lane >> 4;
        val = (m < 4) ? w4[m * 64 + blk * 32 + q * 8 + j] : 0.f;
    }
    ws[idx] = f2bf(val);
}

// LDS (ushort units), XOR-swizzled rows: element (row, ch) at
//   base + row*W + ((ch/8 ^ (row&7))*8) + ch%8      (W = channels, pow2, no pad)
//   ts  @0      16x512  (8192)
//   h1s @8192   16x256  (4096)
//   h2s @12288  16x128  (2048)
//   m3s alias h1s @8192   16x64 (1024)
//   lgs alias h1s @9216   4x16 f32 (128 ush)
//   xp  @14336  308 f32 (616)
// total 14952 ush = 29904 B -> 5 blocks/CU
template <int NS>
__global__ __launch_bounds__(256, 5) void fused_mfma(
    const float* __restrict__ x, const ushort_t* __restrict__ ws,
    const float* __restrict__ b1, const float* __restrict__ b2,
    const float* __restrict__ b3, const float* __restrict__ b4,
    float* __restrict__ part)
{
    __shared__ __align__(16) ushort_t sm[14952];
    ushort_t* const ts  = sm;
    ushort_t* const h1s = sm + 8192;
    ushort_t* const h2s = sm + 12288;
    ushort_t* const m3s = sm + 8192;
    float*   const lgs  = (float*)(sm + 9216);
    float*   const xp   = (float*)(sm + 14336);

    constexpr int SH  = (NS == 4) ? 2 : ((NS == 2) ? 1 : 0);
    constexpr int TPS = (NTILES + NS - 1) / NS;
    const int tid = threadIdx.x;
    const int s   = blockIdx.x & (NS - 1);
    const int bb  = blockIdx.x >> SH;
    const int t0  = s * TPS;
    const int t1  = (t0 + TPS < NTILES) ? (t0 + TPS) : NTILES;

    const int wid  = tid >> 6;
    const int lane = tid & 63;
    const int n0   = lane & 15;
    const int qi   = lane >> 4;
    const int sx   = n0 & 7;
    const int row0 = qi * 4;

    for (int jj = tid; jj < 308; jj += 256) {
        float v = 0.f;
        const int src = jj - 2;
        if (src >= 0 && src < 300) v = x[bb * 300 + src];
        xp[jj] = v;
    }
    __syncthreads();

    const short8* wf1 = (const short8*)(ws);
    const short8* wf2 = (const short8*)(ws + 131072);
    const short8* wf3 = (const short8*)(ws + 163840);
    const short8* wf4 = (const short8*)(ws + 172032);

    const int qh   = (tid >> 5) & 3;   // head
    const int ch   = tid & 127;        // = qh*32 + dd
    const int half = tid >> 7;         // position half within tile
    float M = -1e30f, S = 0.f, A = 0.f;
    const f32x4 z4 = {0.f, 0.f, 0.f, 0.f};

    for (int tile = t0; tile < t1; ++tile) {
        const int pos0 = tile * 16;

        // ---- build t tile: thread = (p = tid&15, j1 = tid>>4), loop i1 ----
        {
            const int p  = tid & 15;
            const int j1 = tid >> 4;
            int posg = pos0 + p; if (posg > 360) posg = 360;
            const int hh = posg / 19;
            const int ww = posg - 19 * hh;
            const float uu  = xp[j1 * 19 + ww];
            const int base  = p * 512;
            const int psw   = p & 7;
            const int octb  = j1 >> 2;
            const int e     = (j1 & 3) * 2;
            #pragma unroll
            for (int i1 = 0; i1 < 16; ++i1) {
                const float v  = xp[i1 * 19 + hh];
                const float di = uu - v;
                const float nd = di * __builtin_amdgcn_rcpf(uu + v + 1e-5f);
                const int oct  = i1 * 4 + octb;
                *(unsigned*)&ts[base + (((oct ^ psw)) << 3) + e] = pkbf(di, nd);
            }
        }
        __syncthreads();

        // ---- layer 1: 256 outs, K=512; wave = 4 outsubs ----
        {
            f32x4 acc[4] = {z4, z4, z4, z4};
            const int tb = n0 * 512;
            const int wbase = wid * 4096 + lane;
            #pragma unroll 4
            for (int ks = 0; ks < 16; ++ks) {
                const int oct = ks * 4 + qi;
                const short8 bbv = *(const short8*)&ts[tb + ((oct ^ sx) << 3)];
                #pragma unroll
                for (int jo = 0; jo < 4; ++jo) {
                    const short8 a = wf1[wbase + (jo * 16 + ks) * 64];
                    acc[jo] = __builtin_amdgcn_mfma_f32_16x16x32_bf16(a, bbv, acc[jo], 0, 0, 0);
                }
            }
            #pragma unroll
            for (int jo = 0; jo < 4; ++jo) {
                const int out0 = (wid * 4 + jo) * 16 + row0;
                const f32x4 bv = *(const f32x4*)&b1[out0];
                const f32x4 a4 = acc[jo];
                uint2 pk;
                pk.x = pkbf(leaky(a4.x + bv.x), leaky(a4.y + bv.y));
                pk.y = pkbf(leaky(a4.z + bv.z), leaky(a4.w + bv.w));
                *(uint2*)&h1s[n0 * 256 + (((out0 >> 3) ^ sx) << 3) + (out0 & 7)] = pk;
            }
        }
        __syncthreads();

        // ---- layer 2: 128 outs, K=256; wave = 2 outsubs ----
        {
            f32x4 acc[2] = {z4, z4};
            const int hb = n0 * 256;
            const int wbase = wid * 1024 + lane;
            #pragma unroll
            for (int ks = 0; ks < 8; ++ks) {
                const int oct = ks * 4 + qi;
                const short8 bbv = *(const short8*)&h1s[hb + ((oct ^ sx) << 3)];
                #pragma unroll
                for (int jo = 0; jo < 2; ++jo) {
                    const short8 a = wf2[wbase + (jo * 8 + ks) * 64];
                    acc[jo] = __builtin_amdgcn_mfma_f32_16x16x32_bf16(a, bbv, acc[jo], 0, 0, 0);
                }
            }
            #pragma unroll
            for (int jo = 0; jo < 2; ++jo) {
                const int out0 = (wid * 2 + jo) * 16 + row0;
                const f32x4 bv = *(const f32x4*)&b2[out0];
                const f32x4 a4 = acc[jo];
                uint2 pk;
                pk.x = pkbf(leaky(a4.x + bv.x), leaky(a4.y + bv.y));
                pk.y = pkbf(leaky(a4.z + bv.z), leaky(a4.w + bv.w));
                *(uint2*)&h2s[n0 * 128 + (((out0 >> 3) ^ sx) << 3) + (out0 & 7)] = pk;
            }
        }
        __syncthreads();

        // ---- layer 3: 64 outs, K=128; wave = 1 outsub (writes alias h1s) ----
        {
            f32x4 acc = z4;
            const int cb = n0 * 128;
            #pragma unroll
            for (int ks = 0; ks < 4; ++ks) {
                const int oct = ks * 4 + qi;
                const short8 bbv = *(const short8*)&h2s[cb + ((oct ^ sx) << 3)];
                const short8 a = wf3[(wid * 4 + ks) * 64 + lane];
                acc = __builtin_amdgcn_mfma_f32_16x16x32_bf16(a, bbv, acc, 0, 0, 0);
            }
            const int out0 = wid * 16 + row0;
            const f32x4 bv = *(const f32x4*)&b3[out0];
            uint2 pk;
            pk.x = pkbf(fmaxf(acc.x + bv.x, 0.f), fmaxf(acc.y + bv.y, 0.f));
            pk.y = pkbf(fmaxf(acc.z + bv.z, 0.f), fmaxf(acc.w + bv.w, 0.f));
            *(uint2*)&m3s[n0 * 64 + (((out0 >> 3) ^ sx) << 3) + (out0 & 7)] = pk;
        }
        __syncthreads();

        // ---- layer 4: 4 outs, K=64 (wave 0) -> masked logits ----
        if (wid == 0) {
            f32x4 acc = z4;
            const int mb = n0 * 64;
            #pragma unroll
            for (int ks = 0; ks < 2; ++ks) {
                const int oct = ks * 4 + qi;
                const short8 bbv = *(const short8*)&m3s[mb + ((oct ^ sx) << 3)];
                const short8 a = wf4[ks * 64 + lane];
                acc = __builtin_amdgcn_mfma_f32_16x16x32_bf16(a, bbv, acc, 0, 0, 0);
            }
            if (lane < 16) {
                const f32x4 bv = *(const f32x4*)&b4[0];
                const bool bad = (pos0 + lane) > 360;
                lgs[0 * 16 + lane] = bad ? -1e30f : fmaxf(acc.x + bv.x, 0.f);
                lgs[1 * 16 + lane] = bad ? -1e30f : fmaxf(acc.y + bv.y, 0.f);
                lgs[2 * 16 + lane] = bad ? -1e30f : fmaxf(acc.z + bv.z, 0.f);
                lgs[3 * 16 + lane] = bad ? -1e30f : fmaxf(acc.w + bv.w, 0.f);
            }
        }
        __syncthreads();

        // ---- online softmax partial: 256 threads = 4 heads x 32 ch x 2 halves ----
        {
            float l[8];
            float tmax = -1e30f;
            #pragma unroll
            for (int p8 = 0; p8 < 8; ++p8) {
                l[p8] = lgs[qh * 16 + half * 8 + p8];
                tmax = fmaxf(tmax, l[p8]);
            }
            const float newM  = fmaxf(M, tmax);
            const float alpha = __expf(M - newM);
            float ssum = 0.f, asum = 0.f;
            const int oc = ch >> 3, el = ch & 7;
            #pragma unroll
            for (int p8 = 0; p8 < 8; ++p8) {
                const int p = half * 8 + p8;
                const float ev = __expf(l[p8] - newM);
                ssum += ev;
                asum += ev * bf2f(h2s[p * 128 + ((oc ^ (p & 7)) << 3) + el]);
            }
            S = S * alpha + ssum;
            A = A * alpha + asum;
            M = newM;
        }
        // no trailing barrier: next tile's post-build barrier orders all hazards
    }

    // combine the two position-halves via LDS (reuse ts region), write partials
    float* mbuf = (float*)ts;
    if (half == 1) {
        mbuf[ch] = M; mbuf[128 + ch] = S; mbuf[256 + ch] = A;
    }
    __syncthreads();
    if (half == 0) {
        const float M1 = mbuf[ch], S1 = mbuf[128 + ch], A1 = mbuf[256 + ch];
        const float Mf = fmaxf(M, M1);
        const float e0 = __expf(M - Mf), e1 = __expf(M1 - Mf);
        const int pb  = (s * 512 + bb) * 128 + ch;
        const int sep = NS * 512 * 128;
        part[pb]           = Mf;
        part[pb + sep]     = S * e0 + S1 * e1;
        part[pb + 2 * sep] = A * e0 + A1 * e1;
    }
}

template <int NS>
__global__ void merge_out(const float* __restrict__ part, float* __restrict__ out) {
    const int idx = blockIdx.x * 256 + threadIdx.x;
    if (idx >= 512 * 128) return;
    const int bb = idx >> 7, ch = idx & 127;
    const int sep = NS * 512 * 128;
    float Mf = -1e30f;
    #pragma unroll
    for (int s = 0; s < NS; ++s) Mf = fmaxf(Mf, part[(s * 512 + bb) * 128 + ch]);
    float Sf = 0.f, Af = 0.f;
    #pragma unroll
    for (int s = 0; s < NS; ++s) {
        const int pb = (s * 512 + bb) * 128 + ch;
        const float e = __expf(part[pb] - Mf);
        Sf += part[pb + sep] * e;
        Af += part[pb + 2 * sep] * e;
    }
    out[idx] = Af / Sf;
}

// ---------------- f32 scalar fallback (known-correct, ws-free) ----------------
__global__ __launch_bounds__(256, 2) void fallback_fused(
    const float* __restrict__ x,
    const float* __restrict__ w1, const float* __restrict__ b1,
    const float* __restrict__ w2, const float* __restrict__ b2,
    const float* __restrict__ w3, const float* __restrict__ b3,
    const float* __restrict__ w4, const float* __restrict__ b4,
    float* __restrict__ out)
{
    __shared__ float smf[14644];
    float* const xp  = smf;
    float* const ts  = smf + 308;
    float* const h1s = smf + 8500;
    float* const h2s = smf + 12596;
    float* const m3s = ts;
    float* const lgs = ts + 1024;

    const int tid = threadIdx.x;
    const int b   = blockIdx.x;
    for (int j = tid; j < 308; j += 256) {
        float v = 0.f;
        const int src = j - 2;
        if (src >= 0 && src < 300) v = x[b * 300 + src];
        xp[j] = v;
    }
    __syncthreads();
    const int q = tid >> 5, dd = tid & 31;
    float M = -1e30f, S = 0.f, A = 0.f;
    for (int tile = 0; tile < 23; ++tile) {
        const int pos0 = tile * 16;
        {
            const int p = tid & 15, kk0 = tid >> 4;
            const int pos = pos0 + p;
            const bool valid = (pos < 361);
            const int hh = valid ? (pos / 19) : 0;
            const int ww = valid ? (pos - hh * 19) : 0;
            #pragma unroll
            for (int i = 0; i < 16; ++i) {
                const int kk = kk0 + (i << 4);
                const int i1 = kk >> 4, j1 = kk & 15;
                float di = 0.f, ndi = 0.f;
                if (valid) {
                    const float u = xp[j1 * 19 + ww];
                    const float v = xp[i1 * 19 + hh];
                    di = u - v; ndi = di / (u + v + 1e-5f);
                }
                ts[(kk << 4) + p] = di;
                ts[((kk + 256) << 4) + p] = ndi;
            }
        }
        __syncthreads();
        {
            const int o = tid;
            float acc[16];
            const float bias = b1[o];
            #pragma unroll
            for (int p = 0; p < 16; ++p) acc[p] = bias;
            for (int k = 0; k < 512; ++k) {
                const int kk = (k >> 1) + (k & 1) * 256;  // ch k maps: even=DI block, odd=NDI block
                const float wv = w1[o * 512 + k];
                #pragma unroll
                for (int p = 0; p < 16; ++p) acc[p] += wv * ts[(kk << 4) + p];
            }
            #pragma unroll
            for (int p = 0; p < 16; ++p) h1s[(o << 4) + p] = leaky(acc[p]);
        }
        __syncthreads();
        {
            const int o2 = tid & 127, pb = (tid >> 7) << 3;
            float acc[8];
            const float bias = b2[o2];
            #pragma unroll
            for (int j = 0; j < 8; ++j) acc[j] = bias;
            for (int k = 0; k < 256; ++k) {
                const float wv = w2[o2 * 256 + k];
                #pragma unroll
                for (int j = 0; j < 8; ++j) acc[j] += wv * h1s[(k << 4) + pb + j];
            }
            #pragma unroll
            for (int j = 0; j < 8; ++j) h2s[(o2 << 4) + pb + j] = leaky(acc[j]);
        }
        __syncthreads();
        {
            const int o3 = tid & 63, pb = (tid >> 6) << 2;
            float acc[4];
            const float bias = b3[o3];
            #pragma unroll
            for (int j = 0; j < 4; ++j) acc[j] = bias;
            for (int k = 0; k < 128; ++k) {
                const float wv = w3[o3 * 128 + k];
                #pragma unroll
                for (int j = 0; j < 4; ++j) acc[j] += wv * h2s[(k << 4) + pb + j];
            }
            #pragma unroll
            for (int j = 0; j < 4; ++j) m3s[(o3 << 4) + pb + j] = fmaxf(acc[j], 0.f);
        }
        __syncthreads();
        if (tid < 64) {
            const int o4 = tid >> 4, p = tid & 15;
            float a = b4[o4];
            for (int k = 0; k < 64; ++k) a += w4[o4 * 64 + k] * m3s[(k << 4) + p];
            a = fmaxf(a, 0.f);
            if (pos0 + p >= 361) a = -1e30f;
            lgs[(o4 << 4) + p] = a;
        }
        __syncthreads();
        if (tid < 128) {
            float l[16];
            #pragma unroll
            for (int p = 0; p < 16; ++p) l[p] = lgs[(q << 4) + p];
            float tmax = l[0];
            #pragma unroll
            for (int p = 1; p < 16; ++p) tmax = fmaxf(tmax, l[p]);
            const float newM = fmaxf(M, tmax);
            const float alpha = __expf(M - newM);
            float ssum = 0.f, asum = 0.f;
            #pragma unroll
            for (int p = 0; p < 16; ++p) {
                const float e = __expf(l[p] - newM);
                ssum += e;
                asum += e * h2s[(((q << 5) + dd) << 4) + p];
            }
            S = S * alpha + ssum; A = A * alpha + asum; M = newM;
        }
        __syncthreads();
    }
    if (tid < 128) out[(b << 7) + tid] = A / S;
}

extern "C" void kernel_launch(void* const* d_in, const int* in_sizes, int n_in,
                              void* d_out, int out_size, void* d_ws, size_t ws_size,
                              hipStream_t stream) {
    const float* x  = (const float*)d_in[0];
    const float* w1 = (const float*)d_in[1];
    const float* b1 = (const float*)d_in[2];
    const float* w2 = (const float*)d_in[3];
    const float* b2 = (const float*)d_in[4];
    const float* w3 = (const float*)d_in[5];
    const float* b3 = (const float*)d_in[6];
    const float* w4 = (const float*)d_in[7];
    const float* b4 = (const float*)d_in[8];
    float* out = (float*)d_out;

    const size_t wbytes = (size_t)WS_W_USHORTS * sizeof(ushort_t);
    const size_t pbytes1 = (size_t)3 * 512 * 128 * sizeof(float);
    ushort_t* ws = (ushort_t*)d_ws;
    float* partf = (float*)((char*)d_ws + wbytes);

    if (ws_size >= wbytes + 4 * pbytes1) {
        pack_weights<<<676, 256, 0, stream>>>(w1, w2, w3, w4, ws);
        fused_mfma<4><<<2048, 256, 0, stream>>>(x, ws, b1, b2, b3, b4, partf);
        merge_out<4><<<256, 256, 0, stream>>>(partf, out);
    } else if (ws_size >= wbytes + 2 * pbytes1) {
        pack_weights<<<676, 256, 0, stream>>>(w1, w2, w3, w4, ws);
        fused_mfma<2><<<1024, 256, 0, stream>>>(x, ws, b1, b2, b3, b4, partf);
        merge_out<2><<<256, 256, 0, stream>>>(partf, out);
    } else if (ws_size >= wbytes + pbytes1) {
        pack_weights<<<676, 256, 0, stream>>>(w1, w2, w3, w4, ws);
        fused_mfma<1><<<512, 256, 0, stream>>>(x, ws, b1, b2, b3, b4, partf);
        merge_out<1><<<256, 256, 0, stream>>>(partf, out);
    } else {
        fallback_fused<<<512, 256, 0, stream>>>(x, w1, b1, w2, b2, w3, b3, w4, b4, out);
    }
}

// Round 4
// 164.861 us; speedup vs baseline: 3.0486x; 3.0486x over previous
//
#include <hip/hip_runtime.h>
#include <math.h>

typedef unsigned short ushort_t;
typedef __attribute__((ext_vector_type(8))) short short8;
typedef __attribute__((ext_vector_type(4))) float f32x4;

#define NTILES 12   // 12 tiles x 32 positions = 384 >= 361

// ws ushort layout (bf16 MFMA A-fragments, lane-major 16B blocks):
//   L1 @0      : 16 outsub x 9 kstep x 64 lane x 8 = 73728   (K=288: 256 NDI + 16 u(colsum) + 16 v(-rowsum))
//   L2 @73728  :  8 outsub x 8 kstep x 64 lane x 8 = 32768
//   L3 @106496 :  4 outsub x 4 kstep x 64 lane x 8 =  8192
//   L4 @114688 :  2 kstep x 64 lane x 8            =  1024 (rows 4..15 zero)
#define WS_W_USHORTS 115712

__device__ inline float bf2f(ushort_t h) { return __uint_as_float(((unsigned)h) << 16); }
__device__ inline ushort_t f2bf(float f) {
    unsigned u = __float_as_uint(f);
    return (ushort_t)((u + 0x7FFFu + ((u >> 16) & 1u)) >> 16);
}
__device__ inline unsigned pkbf(float f0, float f1) {
    unsigned a = __float_as_uint(f0) + 0x8000u;
    unsigned b = __float_as_uint(f1) + 0x8000u;
    return __builtin_amdgcn_perm(b, a, 0x07060302u);
}
__device__ inline float leaky(float v) { return v >= 0.f ? v : 0.01f * v; }

__global__ void pack_weights(const float* __restrict__ w1, const float* __restrict__ w2,
                             const float* __restrict__ w3, const float* __restrict__ w4,
                             ushort_t* __restrict__ ws) {
    const int idx = blockIdx.x * 256 + threadIdx.x;
    if (idx >= WS_W_USHORTS) return;
    float val = 0.f;
    if (idx < 73728) {
        const int j = idx & 7, lane = (idx >> 3) & 63, blk = idx >> 9;
        const int ks = blk % 9, os = blk / 9;
        const int m = lane & 15, q = lane >> 4;
        const int row = os * 16 + m;
        if (ks < 8) {
            const int k = ks * 32 + q * 8 + j;
            const int i1 = k >> 4, j1 = k & 15;
            val = w1[row * 512 + i1 * 32 + j1 * 2 + 1];      // NDI weight (c=1)
        } else {
            const int sub = q * 8 + j;
            if (sub < 16) {                                  // u coeff: colsum of DI weights
                const int j1 = sub;
                float s = 0.f;
                #pragma unroll
                for (int i1 = 0; i1 < 16; ++i1) s += w1[row * 512 + i1 * 32 + j1 * 2];
                val = s;
            } else {                                         // v coeff: -rowsum of DI weights
                const int i1 = sub - 16;
                float s = 0.f;
                #pragma unroll
                for (int j1 = 0; j1 < 16; ++j1) s += w1[row * 512 + i1 * 32 + j1 * 2];
                val = -s;
            }
        }
    } else if (idx < 106496) {
        const int l = idx - 73728;
        const int j = l & 7, lane = (l >> 3) & 63, blk = l >> 9;
        const int ks = blk & 7, os = blk >> 3;
        const int m = lane & 15, q = lane >> 4;
        val = w2[(os * 16 + m) * 256 + ks * 32 + q * 8 + j];
    } else if (idx < 114688) {
        const int l = idx - 106496;
        const int j = l & 7, lane = (l >> 3) & 63, blk = l >> 9;
        const int ks = blk & 3, os = blk >> 2;
        const int m = lane & 15, q = lane >> 4;
        val = w3[(os * 16 + m) * 128 + ks * 32 + q * 8 + j];
    } else {
        const int l = idx - 114688;
        const int j = l & 7, lane = (l >> 3) & 63, ks = l >> 9;
        const int m = lane & 15, q = lane >> 4;
        val = (m < 4) ? w4[m * 64 + ks * 32 + q * 8 + j] : 0.f;
    }
    ws[idx] = f2bf(val);
}

// LDS (ushort units), XOR-swizzled: element (row, oct) at base + row*STR + ((oct ^ (row&7))*8)
//   ts  @0      32 x 320 (288 ch used + pad)  = 10240
//   h1s @10240  32 x 256                      =  8192
//   h2s @18432  32 x 128                      =  4096
//   m3s alias h1s @10240  32 x 64             = (2048)
//   lgs alias (float*)(sm+12288) 4 x 32 f32   = (256)
//   xp  @22528  308 f32                       =   616
// total 23144 ush = 46288 B -> 3 blocks/CU (LDS-limited)
template <int NS>
__global__ __launch_bounds__(256, 3) void fused_mfma(
    const float* __restrict__ x, const ushort_t* __restrict__ ws,
    const float* __restrict__ b1, const float* __restrict__ b2,
    const float* __restrict__ b3, const float* __restrict__ b4,
    float* __restrict__ part)
{
    __shared__ __align__(16) ushort_t sm[23144];
    ushort_t* const ts  = sm;
    ushort_t* const h1s = sm + 10240;
    ushort_t* const h2s = sm + 18432;
    ushort_t* const m3s = sm + 10240;
    float*   const lgs  = (float*)(sm + 12288);
    float*   const xp   = (float*)(sm + 22528);

    constexpr int SH  = (NS == 4) ? 2 : ((NS == 2) ? 1 : 0);
    constexpr int TPS = (NTILES + NS - 1) / NS;
    const int tid = threadIdx.x;
    const int s   = blockIdx.x & (NS - 1);
    const int bb  = blockIdx.x >> SH;
    const int t0  = s * TPS;
    const int t1  = (t0 + TPS < NTILES) ? (t0 + TPS) : NTILES;

    const int wid  = tid >> 6;
    const int lane = tid & 63;
    const int n0   = lane & 15;
    const int qi   = lane >> 4;
    const int sx   = n0 & 7;
    const int row0 = qi * 4;

    for (int jj = tid; jj < 308; jj += 256) {
        float v = 0.f;
        const int src = jj - 2;
        if (src >= 0 && src < 300) v = x[bb * 300 + src];
        xp[jj] = v;
    }
    __syncthreads();

    const short8* wf1 = (const short8*)(ws);
    const short8* wf2 = (const short8*)(ws + 73728);
    const short8* wf3 = (const short8*)(ws + 106496);
    const short8* wf4 = (const short8*)(ws + 114688);

    const int qh   = (tid >> 5) & 3;   // head
    const int ch   = tid & 127;
    const int half = tid >> 7;         // position half (16 each)
    float M = -1e30f, S = 0.f, A = 0.f;
    const f32x4 z4 = {0.f, 0.f, 0.f, 0.f};

    for (int tile = t0; tile < t1; ++tile) {
        const int pos0 = tile * 32;

        // ---- build t tile: thread = (p = tid&31, i1b = tid>>5 in 0..7), i1 in {i1b, i1b+8} ----
        {
            const int p   = tid & 31;
            const int i1b = tid >> 5;
            int posg = pos0 + p; if (posg > 360) posg = 360;
            const int hh = posg / 19;
            const int ww = posg - 19 * hh;
            const int base = p * 320;
            const int psw  = p & 7;
            float u[16];
            #pragma unroll
            for (int j1 = 0; j1 < 16; ++j1) u[j1] = xp[j1 * 19 + ww];
            #pragma unroll
            for (int ii = 0; ii < 2; ++ii) {
                const int i1 = i1b + ii * 8;
                const float v = xp[i1 * 19 + hh];
                #pragma unroll
                for (int j1 = 0; j1 < 16; j1 += 2) {
                    const float nd0 = (u[j1] - v)     * __builtin_amdgcn_rcpf(u[j1] + v + 1e-5f);
                    const float nd1 = (u[j1 + 1] - v) * __builtin_amdgcn_rcpf(u[j1 + 1] + v + 1e-5f);
                    const int oct = i1 * 2 + (j1 >> 3);
                    *(unsigned*)&ts[base + ((oct ^ psw) << 3) + (j1 & 7)] = pkbf(nd0, nd1);
                }
            }
            if (i1b == 0) {  // u/v extension columns (ch 256..287)
                #pragma unroll
                for (int j1 = 0; j1 < 16; j1 += 2) {
                    const int oct = 32 + (j1 >> 3);
                    *(unsigned*)&ts[base + ((oct ^ psw) << 3) + (j1 & 7)] = pkbf(u[j1], u[j1 + 1]);
                }
                #pragma unroll
                for (int i1 = 0; i1 < 16; i1 += 2) {
                    const float v0 = xp[i1 * 19 + hh];
                    const float v1 = xp[(i1 + 1) * 19 + hh];
                    const int oct = 34 + (i1 >> 3);
                    *(unsigned*)&ts[base + ((oct ^ psw) << 3) + (i1 & 7)] = pkbf(v0, v1);
                }
            }
        }
        __syncthreads();

        // ---- layer 1: 256 outs, K=288 (9 ksteps); wave = 4 outsubs x 2 possubs ----
        {
            f32x4 acc[4][2];
            #pragma unroll
            for (int jo = 0; jo < 4; ++jo) { acc[jo][0] = z4; acc[jo][1] = z4; }
            const int tb0 = n0 * 320;
            const int tb1 = tb0 + 16 * 320;
            const int wbase = wid * 2304 + lane;
            #pragma unroll 3
            for (int ks = 0; ks < 9; ++ks) {
                const int oct = ks * 4 + qi;
                const short8 bb0 = *(const short8*)&ts[tb0 + ((oct ^ sx) << 3)];
                const short8 bb1 = *(const short8*)&ts[tb1 + ((oct ^ sx) << 3)];
                #pragma unroll
                for (int jo = 0; jo < 4; ++jo) {
                    const short8 a = wf1[wbase + (jo * 9 + ks) * 64];
                    acc[jo][0] = __builtin_amdgcn_mfma_f32_16x16x32_bf16(a, bb0, acc[jo][0], 0, 0, 0);
                    acc[jo][1] = __builtin_amdgcn_mfma_f32_16x16x32_bf16(a, bb1, acc[jo][1], 0, 0, 0);
                }
            }
            #pragma unroll
            for (int jo = 0; jo < 4; ++jo) {
                const int out0 = (wid * 4 + jo) * 16 + row0;
                const f32x4 bv = *(const f32x4*)&b1[out0];
                #pragma unroll
                for (int ps = 0; ps < 2; ++ps) {
                    const f32x4 a4 = acc[jo][ps];
                    uint2 pk;
                    pk.x = pkbf(leaky(a4.x + bv.x), leaky(a4.y + bv.y));
                    pk.y = pkbf(leaky(a4.z + bv.z), leaky(a4.w + bv.w));
                    *(uint2*)&h1s[(ps * 16 + n0) * 256 + (((out0 >> 3) ^ sx) << 3) + (out0 & 7)] = pk;
                }
            }
        }
        __syncthreads();

        // ---- layer 2: 128 outs, K=256; wave = 2 outsubs x 2 possubs ----
        {
            f32x4 acc[2][2];
            #pragma unroll
            for (int jo = 0; jo < 2; ++jo) { acc[jo][0] = z4; acc[jo][1] = z4; }
            const int hb0 = n0 * 256;
            const int hb1 = hb0 + 16 * 256;
            const int wbase = wid * 1024 + lane;
            #pragma unroll 4
            for (int ks = 0; ks < 8; ++ks) {
                const int oct = ks * 4 + qi;
                const short8 bb0 = *(const short8*)&h1s[hb0 + ((oct ^ sx) << 3)];
                const short8 bb1 = *(const short8*)&h1s[hb1 + ((oct ^ sx) << 3)];
                #pragma unroll
                for (int jo = 0; jo < 2; ++jo) {
                    const short8 a = wf2[wbase + (jo * 8 + ks) * 64];
                    acc[jo][0] = __builtin_amdgcn_mfma_f32_16x16x32_bf16(a, bb0, acc[jo][0], 0, 0, 0);
                    acc[jo][1] = __builtin_amdgcn_mfma_f32_16x16x32_bf16(a, bb1, acc[jo][1], 0, 0, 0);
                }
            }
            #pragma unroll
            for (int jo = 0; jo < 2; ++jo) {
                const int out0 = (wid * 2 + jo) * 16 + row0;
                const f32x4 bv = *(const f32x4*)&b2[out0];
                #pragma unroll
                for (int ps = 0; ps < 2; ++ps) {
                    const f32x4 a4 = acc[jo][ps];
                    uint2 pk;
                    pk.x = pkbf(leaky(a4.x + bv.x), leaky(a4.y + bv.y));
                    pk.y = pkbf(leaky(a4.z + bv.z), leaky(a4.w + bv.w));
                    *(uint2*)&h2s[(ps * 16 + n0) * 128 + (((out0 >> 3) ^ sx) << 3) + (out0 & 7)] = pk;
                }
            }
        }
        __syncthreads();

        // ---- layer 3: 64 outs, K=128; wave = 1 outsub x 2 possubs (writes alias h1s) ----
        {
            f32x4 acc[2] = {z4, z4};
            const int cb0 = n0 * 128;
            const int cb1 = cb0 + 16 * 128;
            #pragma unroll
            for (int ks = 0; ks < 4; ++ks) {
                const int oct = ks * 4 + qi;
                const short8 bb0 = *(const short8*)&h2s[cb0 + ((oct ^ sx) << 3)];
                const short8 bb1 = *(const short8*)&h2s[cb1 + ((oct ^ sx) << 3)];
                const short8 a = wf3[(wid * 4 + ks) * 64 + lane];
                acc[0] = __builtin_amdgcn_mfma_f32_16x16x32_bf16(a, bb0, acc[0], 0, 0, 0);
                acc[1] = __builtin_amdgcn_mfma_f32_16x16x32_bf16(a, bb1, acc[1], 0, 0, 0);
            }
            const int out0 = wid * 16 + row0;
            const f32x4 bv = *(const f32x4*)&b3[out0];
            #pragma unroll
            for (int ps = 0; ps < 2; ++ps) {
                const f32x4 a4 = acc[ps];
                uint2 pk;
                pk.x = pkbf(fmaxf(a4.x + bv.x, 0.f), fmaxf(a4.y + bv.y, 0.f));
                pk.y = pkbf(fmaxf(a4.z + bv.z, 0.f), fmaxf(a4.w + bv.w, 0.f));
                *(uint2*)&m3s[(ps * 16 + n0) * 64 + (((out0 >> 3) ^ sx) << 3) + (out0 & 7)] = pk;
            }
        }
        __syncthreads();

        // ---- layer 4: 4 outs, K=64 (wave 0) -> masked logits ----
        if (wid == 0) {
            f32x4 acc[2] = {z4, z4};
            const int mb0 = n0 * 64;
            const int mb1 = mb0 + 16 * 64;
            #pragma unroll
            for (int ks = 0; ks < 2; ++ks) {
                const int oct = ks * 4 + qi;
                const short8 bb0 = *(const short8*)&m3s[mb0 + ((oct ^ sx) << 3)];
                const short8 bb1 = *(const short8*)&m3s[mb1 + ((oct ^ sx) << 3)];
                const short8 a = wf4[ks * 64 + lane];
                acc[0] = __builtin_amdgcn_mfma_f32_16x16x32_bf16(a, bb0, acc[0], 0, 0, 0);
                acc[1] = __builtin_amdgcn_mfma_f32_16x16x32_bf16(a, bb1, acc[1], 0, 0, 0);
            }
            if (lane < 16) {
                const f32x4 bv = *(const f32x4*)&b4[0];
                #pragma unroll
                for (int ps = 0; ps < 2; ++ps) {
                    const int pos = ps * 16 + lane;
                    const bool bad = (pos0 + pos) > 360;
                    const f32x4 a4 = acc[ps];
                    lgs[0 * 32 + pos] = bad ? -1e30f : fmaxf(a4.x + bv.x, 0.f);
                    lgs[1 * 32 + pos] = bad ? -1e30f : fmaxf(a4.y + bv.y, 0.f);
                    lgs[2 * 32 + pos] = bad ? -1e30f : fmaxf(a4.z + bv.z, 0.f);
                    lgs[3 * 32 + pos] = bad ? -1e30f : fmaxf(a4.w + bv.w, 0.f);
                }
            }
        }
        __syncthreads();

        // ---- online softmax partial: 256 threads = 2 halves x (4 heads x 32 ch) ----
        {
            float l[16];
            float tmax = -1e30f;
            #pragma unroll
            for (int p8 = 0; p8 < 16; ++p8) {
                l[p8] = lgs[qh * 32 + half * 16 + p8];
                tmax = fmaxf(tmax, l[p8]);
            }
            const float newM  = fmaxf(M, tmax);
            const float alpha = __expf(M - newM);
            float ssum = 0.f, asum = 0.f;
            const int oc = ch >> 3, el = ch & 7;
            #pragma unroll
            for (int p8 = 0; p8 < 16; ++p8) {
                const int p = half * 16 + p8;
                const float ev = __expf(l[p8] - newM);
                ssum += ev;
                asum += ev * bf2f(h2s[p * 128 + ((oc ^ (p & 7)) << 3) + el]);
            }
            S = S * alpha + ssum;
            A = A * alpha + asum;
            M = newM;
        }
        // no trailing barrier: next tile's post-build barrier orders ts/h1s hazards
    }

    // combine the two position-halves (reuse ts region), write partials
    float* mbuf = (float*)ts;
    if (half == 1) {
        mbuf[ch] = M; mbuf[128 + ch] = S; mbuf[256 + ch] = A;
    }
    __syncthreads();
    if (half == 0) {
        const float M1 = mbuf[ch], S1 = mbuf[128 + ch], A1 = mbuf[256 + ch];
        const float Mf = fmaxf(M, M1);
        const float e0 = __expf(M - Mf), e1 = __expf(M1 - Mf);
        const int pb  = (s * 512 + bb) * 128 + ch;
        const int sep = NS * 512 * 128;
        part[pb]           = Mf;
        part[pb + sep]     = S * e0 + S1 * e1;
        part[pb + 2 * sep] = A * e0 + A1 * e1;
    }
}

template <int NS>
__global__ void merge_out(const float* __restrict__ part, float* __restrict__ out) {
    const int idx = blockIdx.x * 256 + threadIdx.x;
    if (idx >= 512 * 128) return;
    const int bb = idx >> 7, ch = idx & 127;
    const int sep = NS * 512 * 128;
    float Mf = -1e30f;
    #pragma unroll
    for (int s = 0; s < NS; ++s) Mf = fmaxf(Mf, part[(s * 512 + bb) * 128 + ch]);
    float Sf = 0.f, Af = 0.f;
    #pragma unroll
    for (int s = 0; s < NS; ++s) {
        const int pb = (s * 512 + bb) * 128 + ch;
        const float e = __expf(part[pb] - Mf);
        Sf += part[pb + sep] * e;
        Af += part[pb + 2 * sep] * e;
    }
    out[idx] = Af / Sf;
}

// ---------------- f32 scalar fallback (known-correct, ws-free) ----------------
__global__ __launch_bounds__(256, 2) void fallback_fused(
    const float* __restrict__ x,
    const float* __restrict__ w1, const float* __restrict__ b1,
    const float* __restrict__ w2, const float* __restrict__ b2,
    const float* __restrict__ w3, const float* __restrict__ b3,
    const float* __restrict__ w4, const float* __restrict__ b4,
    float* __restrict__ out)
{
    __shared__ float smf[14644];
    float* const xp  = smf;
    float* const ts  = smf + 308;
    float* const h1s = smf + 8500;
    float* const h2s = smf + 12596;
    float* const m3s = ts;
    float* const lgs = ts + 1024;

    const int tid = threadIdx.x;
    const int b   = blockIdx.x;
    for (int j = tid; j < 308; j += 256) {
        float v = 0.f;
        const int src = j - 2;
        if (src >= 0 && src < 300) v = x[b * 300 + src];
        xp[j] = v;
    }
    __syncthreads();
    const int q = tid >> 5, dd = tid & 31;
    float M = -1e30f, S = 0.f, A = 0.f;
    for (int tile = 0; tile < 23; ++tile) {
        const int pos0 = tile * 16;
        {
            const int p = tid & 15, kk0 = tid >> 4;
            const int pos = pos0 + p;
            const bool valid = (pos < 361);
            const int hh = valid ? (pos / 19) : 0;
            const int ww = valid ? (pos - hh * 19) : 0;
            #pragma unroll
            for (int i = 0; i < 16; ++i) {
                const int kk = kk0 + (i << 4);
                const int i1 = kk >> 4, j1 = kk & 15;
                float di = 0.f, ndi = 0.f;
                if (valid) {
                    const float u = xp[j1 * 19 + ww];
                    const float v = xp[i1 * 19 + hh];
                    di = u - v; ndi = di / (u + v + 1e-5f);
                }
                ts[(kk << 5) + p] = di;
                ts[(kk << 5) + 16 + p] = ndi;
            }
        }
        __syncthreads();
        {
            const int o = tid;
            float acc[16];
            const float bias = b1[o];
            #pragma unroll
            for (int p = 0; p < 16; ++p) acc[p] = bias;
            for (int k = 0; k < 512; ++k) {
                const float wv = w1[o * 512 + k];
                #pragma unroll
                for (int p = 0; p < 16; ++p) acc[p] += wv * ts[(k << 4) + p];
            }
            #pragma unroll
            for (int p = 0; p < 16; ++p) h1s[(o << 4) + p] = leaky(acc[p]);
        }
        __syncthreads();
        {
            const int o2 = tid & 127, pb = (tid >> 7) << 3;
            float acc[8];
            const float bias = b2[o2];
            #pragma unroll
            for (int j = 0; j < 8; ++j) acc[j] = bias;
            for (int k = 0; k < 256; ++k) {
                const float wv = w2[o2 * 256 + k];
                #pragma unroll
                for (int j = 0; j < 8; ++j) acc[j] += wv * h1s[(k << 4) + pb + j];
            }
            #pragma unroll
            for (int j = 0; j < 8; ++j) h2s[(o2 << 4) + pb + j] = leaky(acc[j]);
        }
        __syncthreads();
        {
            const int o3 = tid & 63, pb = (tid >> 6) << 2;
            float acc[4];
            const float bias = b3[o3];
            #pragma unroll
            for (int j = 0; j < 4; ++j) acc[j] = bias;
            for (int k = 0; k < 128; ++k) {
                const float wv = w3[o3 * 128 + k];
                #pragma unroll
                for (int j = 0; j < 4; ++j) acc[j] += wv * h2s[(k << 4) + pb + j];
            }
            #pragma unroll
            for (int j = 0; j < 4; ++j) m3s[(o3 << 4) + pb + j] = fmaxf(acc[j], 0.f);
        }
        __syncthreads();
        if (tid < 64) {
            const int o4 = tid >> 4, p = tid & 15;
            float a = b4[o4];
            for (int k = 0; k < 64; ++k) a += w4[o4 * 64 + k] * m3s[(k << 4) + p];
            a = fmaxf(a, 0.f);
            if (pos0 + p >= 361) a = -1e30f;
            lgs[(o4 << 4) + p] = a;
        }
        __syncthreads();
        if (tid < 128) {
            float l[16];
            #pragma unroll
            for (int p = 0; p < 16; ++p) l[p] = lgs[(q << 4) + p];
            float tmax = l[0];
            #pragma unroll
            for (int p = 1; p < 16; ++p) tmax = fmaxf(tmax, l[p]);
            const float newM = fmaxf(M, tmax);
            const float alpha = __expf(M - newM);
            float ssum = 0.f, asum = 0.f;
            #pragma unroll
            for (int p = 0; p < 16; ++p) {
                const float e = __expf(l[p] - newM);
                ssum += e;
                asum += e * h2s[(((q << 5) + dd) << 4) + p];
            }
            S = S * alpha + ssum; A = A * alpha + asum; M = newM;
        }
        __syncthreads();
    }
    if (tid < 128) out[(b << 7) + tid] = A / S;
}

extern "C" void kernel_launch(void* const* d_in, const int* in_sizes, int n_in,
                              void* d_out, int out_size, void* d_ws, size_t ws_size,
                              hipStream_t stream) {
    const float* x  = (const float*)d_in[0];
    const float* w1 = (const float*)d_in[1];
    const float* b1 = (const float*)d_in[2];
    const float* w2 = (const float*)d_in[3];
    const float* b2 = (const float*)d_in[4];
    const float* w3 = (const float*)d_in[5];
    const float* b3 = (const float*)d_in[6];
    const float* w4 = (const float*)d_in[7];
    const float* b4 = (const float*)d_in[8];
    float* out = (float*)d_out;

    const size_t wbytes  = (size_t)WS_W_USHORTS * sizeof(ushort_t);
    const size_t pbytes1 = (size_t)3 * 512 * 128 * sizeof(float);
    ushort_t* ws = (ushort_t*)d_ws;
    float* partf = (float*)((char*)d_ws + wbytes);

    const int packBlocks = (WS_W_USHORTS + 255) / 256;
    if (ws_size >= wbytes + 4 * pbytes1) {
        pack_weights<<<packBlocks, 256, 0, stream>>>(w1, w2, w3, w4, ws);
        fused_mfma<4><<<2048, 256, 0, stream>>>(x, ws, b1, b2, b3, b4, partf);
        merge_out<4><<<256, 256, 0, stream>>>(partf, out);
    } else if (ws_size >= wbytes + 2 * pbytes1) {
        pack_weights<<<packBlocks, 256, 0, stream>>>(w1, w2, w3, w4, ws);
        fused_mfma<2><<<1024, 256, 0, stream>>>(x, ws, b1, b2, b3, b4, partf);
        merge_out<2><<<256, 256, 0, stream>>>(partf, out);
    } else if (ws_size >= wbytes + pbytes1) {
        pack_weights<<<packBlocks, 256, 0, stream>>>(w1, w2, w3, w4, ws);
        fused_mfma<1><<<512, 256, 0, stream>>>(x, ws, b1, b2, b3, b4, partf);
        merge_out<1><<<256, 256, 0, stream>>>(partf, out);
    } else {
        fallback_fused<<<512, 256, 0, stream>>>(x, w1, b1, w2, b2, w3, b3, w4, b4, out);
    }
}